// Round 11
// baseline (233.477 us; speedup 1.0000x reference)
//
#include <hip/hip_runtime.h>
#include <stdint.h>

#define NROWS 16384
#define D 4096

typedef __bf16 bf16x8 __attribute__((ext_vector_type(8)));
typedef float  f32x4  __attribute__((ext_vector_type(4)));

__device__ inline unsigned short f2bf(float f) {
    unsigned u = __float_as_uint(f);
    u += 0x7fffu + ((u >> 16) & 1u);
    return (unsigned short)(u >> 16);
}

// ---------------- Wco build: c1[X][y][z][pqr] = sum_x fo0[X,x] core[x,y,z,pqr]
__global__ __launch_bounds__(256) void k_b1(const float* __restrict__ core,
                                            const float* __restrict__ fo0,
                                            float* __restrict__ c1) {
    int g = blockIdx.x * 256 + threadIdx.x;      // 524288
    int pqr = g & 511, z = (g >> 9) & 7, y = (g >> 12) & 7, X = g >> 15;
    float s = 0.f;
    #pragma unroll
    for (int x = 0; x < 8; ++x)
        s += fo0[X * 8 + x] * core[x * 32768 + y * 4096 + z * 512 + pqr];
    c1[g] = s;
}

// c2[X][Y][z][pqr] = sum_y fo1[Y,y] c1[X,y,z,pqr]
__global__ __launch_bounds__(256) void k_b2(const float* __restrict__ c1,
                                            const float* __restrict__ fo1,
                                            float* __restrict__ c2) {
    int g = blockIdx.x * 256 + threadIdx.x;      // 1048576
    int pqr = g & 511, z = (g >> 9) & 7, Y = (g >> 12) & 15, X = g >> 16;
    float s = 0.f;
    #pragma unroll
    for (int y = 0; y < 8; ++y)
        s += fo1[Y * 8 + y] * c1[X * 32768 + y * 4096 + z * 512 + pqr];
    c2[g] = s;
}

// Wco in GEMM staging layout [kt][k4][n][8bf16] (u32-pair granularity)
__global__ __launch_bounds__(256) void k_b3(const float* __restrict__ c2,
                                            const float* __restrict__ fo2,
                                            unsigned int* __restrict__ wco) {
    int g = blockIdx.x * 256 + threadIdx.x;      // 1048576
    int kp = g & 255, n = g >> 8;                // kp = bf16-pair index, k=2*kp
    int X = n >> 8, Y = (n >> 4) & 15, Z = n & 15;
    float s0 = 0.f, s1 = 0.f;
    #pragma unroll
    for (int z = 0; z < 8; ++z) {
        float2 v = *(const float2*)&c2[X * 65536 + Y * 4096 + z * 512 + 2 * kp];
        float f = fo2[Z * 8 + z];
        s0 += f * v.x; s1 += f * v.y;
    }
    const int kt = kp >> 5, k4 = (kp >> 2) & 7, w = kp & 3;
    wco[(((size_t)kt * 8 + k4) * 4096 + n) * 4 + w] =
        (unsigned)f2bf(s0) | ((unsigned)f2bf(s1) << 16);
}

// ---------------- input contraction: 4 rows/block, dbuf pipeline ----------------
// (byte-identical to rounds 8/9/10 — verified)
__global__ __launch_bounds__(256, 3) void k_t3(const float* __restrict__ x,
                                               const float* __restrict__ fi0,
                                               const float* __restrict__ fi1,
                                               const float* __restrict__ fi2,
                                               const int* __restrict__ perm,
                                               unsigned int* __restrict__ t3out) {
    __shared__ float xr[2][4096];  // 32 KB, double-buffered un-permuted rows
    __shared__ float t1[2048];     //  8 KB
    __shared__ float t2[1024];     //  4 KB
    __shared__ float fac[3][128];  //  1.5 KB

    const int tid = threadIdx.x;
    const int n0 = blockIdx.x * 4;

    {
        const int h = tid & 127;
        fac[0][h] = fi0[h];
        fac[1][h] = fi1[h];
        fac[2][h] = fi2[h];
    }
    int pj[16];
    #pragma unroll
    for (int j = 0; j < 16; ++j) pj[j] = perm[j * 256 + tid];

    auto stage = [&](int b, int row) {
        const float4* src = (const float4*)(x + (size_t)row * D);
        #pragma unroll
        for (int i = 0; i < 4; ++i) {
            const int c = i * 256 + tid;
            __builtin_amdgcn_global_load_lds(
                (const __attribute__((address_space(1))) void*)(src + c),
                (__attribute__((address_space(3))) void*)(&xr[b][c * 4]),
                16, 0, 0);
        }
    };

    auto STEP3 = [&](int b) {
        float a8[8] = {0,0,0,0,0,0,0,0};
        #pragma unroll
        for (int a = 0; a < 16; ++a) {
            float v = xr[b][pj[a]];
            #pragma unroll
            for (int p = 0; p < 8; ++p) a8[p] += v * fac[0][a * 8 + p];
        }
        #pragma unroll
        for (int p = 0; p < 8; ++p) t1[p * 256 + tid] = a8[p];
    };
    auto STEP4 = [&]() {
        const int p = tid >> 5, c = (tid >> 1) & 15, qh = tid & 1;
        float a4[4] = {0,0,0,0};
        #pragma unroll
        for (int b = 0; b < 16; ++b) {
            float v = t1[p * 256 + b * 16 + c];
            #pragma unroll
            for (int qi = 0; qi < 4; ++qi) a4[qi] += v * fac[1][b * 8 + qh * 4 + qi];
        }
        #pragma unroll
        for (int qi = 0; qi < 4; ++qi) t2[p * 128 + (qh * 4 + qi) * 16 + c] = a4[qi];
    };
    auto STEP5_PACK = [&](int n) {
        const int p = tid >> 5, q = (tid >> 2) & 7, rh = tid & 3;
        float a2[2] = {0,0};
        #pragma unroll
        for (int c = 0; c < 16; ++c) {
            float v = t2[p * 128 + q * 16 + c];
            #pragma unroll
            for (int ri = 0; ri < 2; ++ri) a2[ri] += v * fac[2][c * 8 + rh * 2 + ri];
        }
        const int kt = tid >> 5, k4 = (tid >> 2) & 7, w = tid & 3;
        t3out[(((size_t)kt * 8 + k4) * NROWS + n) * 4 + w] =
            (unsigned)f2bf(a2[0]) | ((unsigned)f2bf(a2[1]) << 16);
    };

    stage(0, n0 + 0);
    stage(1, n0 + 1);

    asm volatile("s_waitcnt vmcnt(4) lgkmcnt(0)" ::: "memory");
    __builtin_amdgcn_s_barrier();
    STEP3(0);
    asm volatile("s_waitcnt lgkmcnt(0)" ::: "memory");
    __builtin_amdgcn_s_barrier();
    stage(0, n0 + 2);
    STEP4();
    asm volatile("s_waitcnt lgkmcnt(0)" ::: "memory");
    __builtin_amdgcn_s_barrier();
    STEP5_PACK(n0 + 0);

    asm volatile("s_waitcnt vmcnt(5)" ::: "memory");
    __builtin_amdgcn_s_barrier();
    STEP3(1);
    asm volatile("s_waitcnt lgkmcnt(0)" ::: "memory");
    __builtin_amdgcn_s_barrier();
    stage(1, n0 + 3);
    STEP4();
    asm volatile("s_waitcnt lgkmcnt(0)" ::: "memory");
    __builtin_amdgcn_s_barrier();
    STEP5_PACK(n0 + 1);

    asm volatile("s_waitcnt vmcnt(6)" ::: "memory");
    __builtin_amdgcn_s_barrier();
    STEP3(0);
    asm volatile("s_waitcnt lgkmcnt(0)" ::: "memory");
    __builtin_amdgcn_s_barrier();
    STEP4();
    asm volatile("s_waitcnt lgkmcnt(0)" ::: "memory");
    __builtin_amdgcn_s_barrier();
    STEP5_PACK(n0 + 2);

    asm volatile("s_waitcnt vmcnt(2)" ::: "memory");
    __builtin_amdgcn_s_barrier();
    STEP3(1);
    asm volatile("s_waitcnt lgkmcnt(0)" ::: "memory");
    __builtin_amdgcn_s_barrier();
    STEP4();
    asm volatile("s_waitcnt lgkmcnt(0)" ::: "memory");
    __builtin_amdgcn_s_barrier();
    STEP5_PACK(n0 + 3);
}

// ---------------- GEMM: out[n][4096] = t3 @ Wco^T + epilogue ----------------
// Tile M=256 x N=128, 256 threads (4 waves 2x2, per-wave 128x64), BK=32,
// double-buffered 48 KB LDS, counted vmcnt(6), 2 blocks/CU (VGPR<=256, LDS 96K).
// Phase: {stage(t+1); vmcnt(6); barrier; sched_barrier; 12 ds_read; MFMA x32
// (setprio); barrier}. Two async blocks/CU interleave barrier stalls.
__global__ __launch_bounds__(256, 2) void k_gemm(const __bf16* __restrict__ t3,
                                                 const __bf16* __restrict__ wco,
                                                 const float* __restrict__ pds,
                                                 const float* __restrict__ alphap,
                                                 const float* __restrict__ bias,
                                                 float* __restrict__ out) {
    __shared__ __bf16 lA[2][8192];   // [buf][k4 0..3][row 0..255][8]  2x16 KB
    __shared__ __bf16 lB[2][4096];   // [buf][k4 0..3][row 0..127][8]  2x8 KB

    const int tid = threadIdx.x, lane = tid & 63, wv = tid >> 6;

    // XCD-chunked bijective swizzle (2048 % 8 == 0), n fastest.
    // 64 m-panels x 32 n-panels; each XCD: 8 contiguous m-panels.
    const int bid = blockIdx.x;
    const int wgid = (bid & 7) * 256 + (bid >> 3);
    const int m0 = (wgid >> 5) * 256;
    const int n0 = (wgid & 31) * 128;
    const int wm = wv >> 1, wn = wv & 1;   // 2 x 2 wave grid
    const int l15 = lane & 15, l4 = lane >> 4;

    // epilogue preload (8 VMEM/lane, OLDEST — drained at first gate)
    const float alpha = alphap[0];
    float pv[4], bv[4];
    #pragma unroll
    for (int nt = 0; nt < 4; ++nt) {
        const int col = n0 + wn * 64 + nt * 16 + l15;
        pv[nt] = pds[col] * alpha;
        bv[nt] = bias[col];
    }

    // stage one BK=32 tile (A 16 KB + B 8 KB): 6 gload_lds/lane, coalesced
    auto stage = [&](int t32) {
        const int b = t32 & 1;
        const int kb = t32 * 4;                      // global 8-elem column group
        #pragma unroll
        for (int i = 0; i < 4; ++i) {                // A: 1024 chunks
            const int c = i * 256 + tid;
            const int k4 = c >> 8, r = c & 255;
            const __bf16* ga = t3 + ((size_t)(kb + k4) * NROWS + m0 + r) * 8;
            __builtin_amdgcn_global_load_lds(
                (const __attribute__((address_space(1))) void*)ga,
                (__attribute__((address_space(3))) void*)(&lA[b][(size_t)c * 8]),
                16, 0, 0);
        }
        #pragma unroll
        for (int i = 0; i < 2; ++i) {                // B: 512 chunks
            const int c = i * 256 + tid;
            const int k4 = c >> 7, r = c & 127;
            const __bf16* gb = wco + ((size_t)(kb + k4) * 4096 + n0 + r) * 8;
            __builtin_amdgcn_global_load_lds(
                (const __attribute__((address_space(1))) void*)gb,
                (__attribute__((address_space(3))) void*)(&lB[b][(size_t)c * 8]),
                16, 0, 0);
        }
    };

    f32x4 acc[8][4] = {};

    stage(0);    // 6 VMEM/lane (+8 older pv/bv)
    #pragma unroll 1
    for (int t = 0; t < 16; ++t) {
        const int buf = t & 1;
        if (t < 15) stage(t + 1);                  // +6, newest
        // gate: tile t resident (drains pv/bv + tile t); tile t+1 in flight
        if (t < 15) asm volatile("s_waitcnt vmcnt(6)" ::: "memory");
        else        asm volatile("s_waitcnt vmcnt(0)" ::: "memory");
        __builtin_amdgcn_s_barrier();              // tile t visible to all waves
        __builtin_amdgcn_sched_barrier(0);         // no ds_read hoist above barrier
        bf16x8 af[8], bfr[4];
        #pragma unroll
        for (int mt = 0; mt < 8; ++mt)
            af[mt] = *(const bf16x8*)&lA[buf][(l4 * 256 + wm * 128 + mt * 16 + l15) * 8];
        #pragma unroll
        for (int nt = 0; nt < 4; ++nt)
            bfr[nt] = *(const bf16x8*)&lB[buf][(l4 * 128 + wn * 64 + nt * 16 + l15) * 8];
        __builtin_amdgcn_s_setprio(1);
        #pragma unroll
        for (int mt = 0; mt < 8; ++mt)
            #pragma unroll
            for (int nt = 0; nt < 4; ++nt)
                acc[mt][nt] = __builtin_amdgcn_mfma_f32_16x16x32_bf16(
                    af[mt], bfr[nt], acc[mt][nt], 0, 0, 0);
        __builtin_amdgcn_s_setprio(0);
        __builtin_amdgcn_s_barrier();              // all reads of buf done (own lgkm
                                                   // drained before MFMA by compiler)
    }

    // epilogue: scale * alpha + bias
    #pragma unroll
    for (int nt = 0; nt < 4; ++nt) {
        const int col = n0 + wn * 64 + nt * 16 + l15;
        #pragma unroll
        for (int mt = 0; mt < 8; ++mt) {
            const int row = m0 + wm * 128 + mt * 16 + l4 * 4;
            #pragma unroll
            for (int j = 0; j < 4; ++j)
                out[(size_t)(row + j) * 4096 + col] = acc[mt][nt][j] * pv[nt] + bv[nt];
        }
    }
}

extern "C" void kernel_launch(void* const* d_in, const int* in_sizes, int n_in,
                              void* d_out, int out_size, void* d_ws, size_t ws_size,
                              hipStream_t stream) {
    const float* x     = (const float*)d_in[0];
    const float* core  = (const float*)d_in[1];
    const float* fi0   = (const float*)d_in[2];
    const float* fi1   = (const float*)d_in[3];
    const float* fi2   = (const float*)d_in[4];
    const float* fo0   = (const float*)d_in[5];
    const float* fo1   = (const float*)d_in[6];
    const float* fo2   = (const float*)d_in[7];
    const float* pds   = (const float*)d_in[8];
    const float* alpha = (const float*)d_in[9];
    const float* bias  = (const float*)d_in[10];
    const int*   perm  = (const int*)d_in[11];
    float* outp = (float*)d_out;

    char* ws = (char*)d_ws;
    float*        c1   = (float*)(ws);                       // 2 MB
    float*        c2   = (float*)(ws + 2097152);             // 4 MB
    unsigned int* wco  = (unsigned int*)(ws + 6291456);      // 4 MB
    unsigned int* t3ws = (unsigned int*)(ws + 10485760);     // 16 MB

    k_b1<<<2048, 256, 0, stream>>>(core, fo0, c1);
    k_b2<<<4096, 256, 0, stream>>>(c1, fo1, c2);
    k_b3<<<4096, 256, 0, stream>>>(c2, fo2, wco);
    k_t3<<<NROWS / 4, 256, 0, stream>>>(x, fi0, fi1, fi2, perm, t3ws);
    k_gemm<<<2048, 256, 0, stream>>>((const __bf16*)t3ws, (const __bf16*)wco,
                                     pds, alpha, bias, outp);
}

// Round 12
// 220.489 us; speedup vs baseline: 1.0589x; 1.0589x over previous
//
#include <hip/hip_runtime.h>
#include <stdint.h>

#define NROWS 16384
#define D 4096

typedef __bf16 bf16x8 __attribute__((ext_vector_type(8)));
typedef float  f32x4  __attribute__((ext_vector_type(4)));

__device__ inline unsigned short f2bf(float f) {
    unsigned u = __float_as_uint(f);
    u += 0x7fffu + ((u >> 16) & 1u);
    return (unsigned short)(u >> 16);
}

// ---------------- core -> bf16 in GEMM staging layout ----------------
// core fp32 is [o=xyz][k=pqr] = [512][512]. Staging layout: element k of row o
// -> u32 index ((k>>3)*512 + o)*4 + ((k>>1)&3). One o-row per block.
__global__ __launch_bounds__(256) void k_corebf(const float* __restrict__ core,
                                                unsigned int* __restrict__ cb) {
    const int o = blockIdx.x;            // 512
    const int kp = threadIdx.x;          // bf16-pair index, k = 2*kp
    float2 v = *(const float2*)&core[o * 512 + 2 * kp];
    cb[((size_t)(kp >> 2) * 512 + o) * 4 + (kp & 3)] =
        (unsigned)f2bf(v.x) | ((unsigned)f2bf(v.y) << 16);
}

// ---------------- input contraction: 4 rows/block, dbuf pipeline ----------------
// (byte-identical to rounds 8-11 — verified)
__global__ __launch_bounds__(256, 3) void k_t3(const float* __restrict__ x,
                                               const float* __restrict__ fi0,
                                               const float* __restrict__ fi1,
                                               const float* __restrict__ fi2,
                                               const int* __restrict__ perm,
                                               unsigned int* __restrict__ t3out) {
    __shared__ float xr[2][4096];  // 32 KB, double-buffered un-permuted rows
    __shared__ float t1[2048];     //  8 KB
    __shared__ float t2[1024];     //  4 KB
    __shared__ float fac[3][128];  //  1.5 KB

    const int tid = threadIdx.x;
    const int n0 = blockIdx.x * 4;

    {
        const int h = tid & 127;
        fac[0][h] = fi0[h];
        fac[1][h] = fi1[h];
        fac[2][h] = fi2[h];
    }
    int pj[16];
    #pragma unroll
    for (int j = 0; j < 16; ++j) pj[j] = perm[j * 256 + tid];

    auto stage = [&](int b, int row) {
        const float4* src = (const float4*)(x + (size_t)row * D);
        #pragma unroll
        for (int i = 0; i < 4; ++i) {
            const int c = i * 256 + tid;
            __builtin_amdgcn_global_load_lds(
                (const __attribute__((address_space(1))) void*)(src + c),
                (__attribute__((address_space(3))) void*)(&xr[b][c * 4]),
                16, 0, 0);
        }
    };

    auto STEP3 = [&](int b) {
        float a8[8] = {0,0,0,0,0,0,0,0};
        #pragma unroll
        for (int a = 0; a < 16; ++a) {
            float v = xr[b][pj[a]];
            #pragma unroll
            for (int p = 0; p < 8; ++p) a8[p] += v * fac[0][a * 8 + p];
        }
        #pragma unroll
        for (int p = 0; p < 8; ++p) t1[p * 256 + tid] = a8[p];
    };
    auto STEP4 = [&]() {
        const int p = tid >> 5, c = (tid >> 1) & 15, qh = tid & 1;
        float a4[4] = {0,0,0,0};
        #pragma unroll
        for (int b = 0; b < 16; ++b) {
            float v = t1[p * 256 + b * 16 + c];
            #pragma unroll
            for (int qi = 0; qi < 4; ++qi) a4[qi] += v * fac[1][b * 8 + qh * 4 + qi];
        }
        #pragma unroll
        for (int qi = 0; qi < 4; ++qi) t2[p * 128 + (qh * 4 + qi) * 16 + c] = a4[qi];
    };
    auto STEP5_PACK = [&](int n) {
        const int p = tid >> 5, q = (tid >> 2) & 7, rh = tid & 3;
        float a2[2] = {0,0};
        #pragma unroll
        for (int c = 0; c < 16; ++c) {
            float v = t2[p * 128 + q * 16 + c];
            #pragma unroll
            for (int ri = 0; ri < 2; ++ri) a2[ri] += v * fac[2][c * 8 + rh * 2 + ri];
        }
        const int kt = tid >> 5, k4 = (tid >> 2) & 7, w = tid & 3;
        t3out[(((size_t)kt * 8 + k4) * NROWS + n) * 4 + w] =
            (unsigned)f2bf(a2[0]) | ((unsigned)f2bf(a2[1]) << 16);
    };

    stage(0, n0 + 0);
    stage(1, n0 + 1);

    asm volatile("s_waitcnt vmcnt(4) lgkmcnt(0)" ::: "memory");
    __builtin_amdgcn_s_barrier();
    STEP3(0);
    asm volatile("s_waitcnt lgkmcnt(0)" ::: "memory");
    __builtin_amdgcn_s_barrier();
    stage(0, n0 + 2);
    STEP4();
    asm volatile("s_waitcnt lgkmcnt(0)" ::: "memory");
    __builtin_amdgcn_s_barrier();
    STEP5_PACK(n0 + 0);

    asm volatile("s_waitcnt vmcnt(5)" ::: "memory");
    __builtin_amdgcn_s_barrier();
    STEP3(1);
    asm volatile("s_waitcnt lgkmcnt(0)" ::: "memory");
    __builtin_amdgcn_s_barrier();
    stage(1, n0 + 3);
    STEP4();
    asm volatile("s_waitcnt lgkmcnt(0)" ::: "memory");
    __builtin_amdgcn_s_barrier();
    STEP5_PACK(n0 + 1);

    asm volatile("s_waitcnt vmcnt(6)" ::: "memory");
    __builtin_amdgcn_s_barrier();
    STEP3(0);
    asm volatile("s_waitcnt lgkmcnt(0)" ::: "memory");
    __builtin_amdgcn_s_barrier();
    STEP4();
    asm volatile("s_waitcnt lgkmcnt(0)" ::: "memory");
    __builtin_amdgcn_s_barrier();
    STEP5_PACK(n0 + 2);

    asm volatile("s_waitcnt vmcnt(2)" ::: "memory");
    __builtin_amdgcn_s_barrier();
    STEP3(1);
    asm volatile("s_waitcnt lgkmcnt(0)" ::: "memory");
    __builtin_amdgcn_s_barrier();
    STEP4();
    asm volatile("s_waitcnt lgkmcnt(0)" ::: "memory");
    __builtin_amdgcn_s_barrier();
    STEP5_PACK(n0 + 3);
}

// ---------------- core GEMM: t4[n][512] = t3[n][512] @ core^T (bf16 out) ------
// Round-9 verified 128x128 counted-vmcnt structure; B = core (512 KB, L2-hot).
__global__ __launch_bounds__(256, 2) void k_core(const __bf16* __restrict__ t3,
                                                 const __bf16* __restrict__ cb,
                                                 unsigned short* __restrict__ t4) {
    __shared__ __bf16 lA[2][8192];   // [buf][k4][row][8]  2x16 KB
    __shared__ __bf16 lB[2][8192];   //                    2x16 KB

    const int tid = threadIdx.x, lane = tid & 63, wv = tid >> 6;

    // bijective XCD swizzle (512 = 8*64), n fastest
    const int bid = blockIdx.x;
    const int wgid = (bid & 7) * 64 + (bid >> 3);
    const int m0 = (wgid >> 2) * 128;     // 128 m-panels
    const int n0 = (wgid & 3) * 128;      // 4 n-panels
    const int wm = wv >> 1, wn = wv & 1;
    const int l15 = lane & 15, l4 = lane >> 4;

    auto stage = [&](int b, int kt) {
        #pragma unroll
        for (int i = 0; i < 4; ++i) {
            const int c = i * 256 + tid;
            const int k4 = c >> 7, r = c & 127;
            const __bf16* ga = t3 + ((size_t)(kt * 8 + k4) * NROWS + m0 + r) * 8;
            __builtin_amdgcn_global_load_lds(
                (const __attribute__((address_space(1))) void*)ga,
                (__attribute__((address_space(3))) void*)(&lA[b][(size_t)c * 8]),
                16, 0, 0);
            const __bf16* gb = cb + ((size_t)(kt * 8 + k4) * 512 + n0 + r) * 8;
            __builtin_amdgcn_global_load_lds(
                (const __attribute__((address_space(1))) void*)gb,
                (__attribute__((address_space(3))) void*)(&lB[b][(size_t)c * 8]),
                16, 0, 0);
        }
    };

    f32x4 acc[4][4] = {};

    auto compute = [&](int cur) {
        #pragma unroll
        for (int kk = 0; kk < 2; ++kk) {
            const int k4f = kk * 4 + l4;
            bf16x8 af[4], bfr[4];
            #pragma unroll
            for (int mt = 0; mt < 4; ++mt)
                af[mt] = *(const bf16x8*)&lA[cur][(k4f * 128 + wm * 64 + mt * 16 + l15) * 8];
            #pragma unroll
            for (int nt = 0; nt < 4; ++nt)
                bfr[nt] = *(const bf16x8*)&lB[cur][(k4f * 128 + wn * 64 + nt * 16 + l15) * 8];
            #pragma unroll
            for (int mt = 0; mt < 4; ++mt)
                #pragma unroll
                for (int nt = 0; nt < 4; ++nt)
                    acc[mt][nt] = __builtin_amdgcn_mfma_f32_16x16x32_bf16(
                        af[mt], bfr[nt], acc[mt][nt], 0, 0, 0);
        }
    };

    stage(0, 0);
    stage(1, 1);
    #pragma unroll 1
    for (int kt = 0; kt < 8; ++kt) {
        if (kt < 7) asm volatile("s_waitcnt vmcnt(8)" ::: "memory");
        else        asm volatile("s_waitcnt vmcnt(0)" ::: "memory");
        __builtin_amdgcn_s_barrier();
        __builtin_amdgcn_s_setprio(1);
        compute(kt & 1);
        __builtin_amdgcn_s_setprio(0);
        __builtin_amdgcn_s_barrier();
        if (kt < 6) stage(kt & 1, kt + 2);
    }

    // epilogue: pack bf16, row-major t4[n][512]
    #pragma unroll
    for (int nt = 0; nt < 4; ++nt) {
        const int col = n0 + wn * 64 + nt * 16 + l15;
        #pragma unroll
        for (int mt = 0; mt < 4; ++mt) {
            const int row = m0 + wm * 64 + mt * 16 + l4 * 4;
            #pragma unroll
            for (int j = 0; j < 4; ++j)
                t4[(size_t)(row + j) * 512 + col] = f2bf(acc[mt][nt][j]);
        }
    }
}

// ---------------- output expansion: 8 rows/block, write-bound ----------------
// t4 row (512 bf16) -> t5(X,y,z) -> t6(X,Y,z) -> out(X,Y,Z)*pds*alpha+bias.
// Quad-staged t4 via global_load_lds + counted vmcnt; LDS layouts audited:
// t5 X-stride 72 (2-way, free), t6 XY-stride 9 (phase-C reads 2-way, free).
// VMEM/thread order: fac(3)+alpha(1)+pds(8)+bias(8)=20, stage0(1), stage1(1),
// then 8 stores/pair. Gates: vmcnt(1) [stage1 in flight], vmcnt(16) before
// pair2 [16 stores newer than stage1].
__global__ __launch_bounds__(256, 3) void k_expand(const unsigned short* __restrict__ t4,
                                                   const float* __restrict__ fo0,
                                                   const float* __restrict__ fo1,
                                                   const float* __restrict__ fo2,
                                                   const float* __restrict__ pds,
                                                   const float* __restrict__ alphap,
                                                   const float* __restrict__ bias,
                                                   float* __restrict__ out) {
    __shared__ unsigned short t4b[2][4][512];  //  8 KB, 2 quads of 4 rows
    __shared__ float t5[2][1152];              //  9 KB, [half][X*72 + y*8 + z]
    __shared__ float t6[2][2304];              // 18 KB, [half][(X*16+Y)*9 + z]
    __shared__ float fac[3][128];              //  1.5 KB

    const int tid = threadIdx.x;
    const int nb = blockIdx.x * 8;
    const int half = tid >> 7, t = tid & 127;

    // fac -> LDS (3 VMEM, oldest)
    {
        const int h = tid & 127;
        fac[0][h] = fo0[h];
        fac[1][h] = fo1[h];
        fac[2][h] = fo2[h];
    }
    // epilogue constants -> regs (1 + 8 + 8 VMEM)
    const float alpha = alphap[0];
    float pv[2][16], bv[2][16];
    #pragma unroll
    for (int h = 0; h < 2; ++h) {
        const int XY = h * 128 + t;
        const int j0 = (XY >> 4) * 256 + (XY & 15) * 16;
        #pragma unroll
        for (int w = 0; w < 4; ++w) {
            float4 p4 = *(const float4*)&pds[j0 + w * 4];
            float4 b4 = *(const float4*)&bias[j0 + w * 4];
            pv[h][w * 4 + 0] = p4.x * alpha; pv[h][w * 4 + 1] = p4.y * alpha;
            pv[h][w * 4 + 2] = p4.z * alpha; pv[h][w * 4 + 3] = p4.w * alpha;
            bv[h][w * 4 + 0] = b4.x; bv[h][w * 4 + 1] = b4.y;
            bv[h][w * 4 + 2] = b4.z; bv[h][w * 4 + 3] = b4.w;
        }
    }

    // stage a quad of 4 t4 rows (4 KB): 1 gload_lds/thread, coalesced
    auto stage = [&](int q) {
        const int row = tid >> 6, off = tid & 63;
        const unsigned short* src = t4 + ((size_t)(nb + q * 4 + row) * 512 + off * 8);
        __builtin_amdgcn_global_load_lds(
            (const __attribute__((address_space(1))) void*)src,
            (__attribute__((address_space(3))) void*)(&t4b[q][row][off * 8]),
            16, 0, 0);
    };

    auto PAIR = [&](int p) {
        const int b = p >> 1;
        const int r_in = (p & 1) * 2 + half;
        const int n = nb + p * 2 + half;
        const int yz = t & 63, xh = t >> 6;
        // phase A: t5[X][yz] = sum_x t4[x*64+yz] * fo0[X,x]
        {
            float a8[8] = {0,0,0,0,0,0,0,0};
            #pragma unroll
            for (int xx = 0; xx < 8; ++xx) {
                float v = __uint_as_float((unsigned)t4b[b][r_in][xx * 64 + yz] << 16);
                #pragma unroll
                for (int Xi = 0; Xi < 8; ++Xi)
                    a8[Xi] += v * fac[0][(xh * 8 + Xi) * 8 + xx];
            }
            #pragma unroll
            for (int Xi = 0; Xi < 8; ++Xi)
                t5[half][(xh * 8 + Xi) * 72 + yz] = a8[Xi];
        }
        asm volatile("s_waitcnt lgkmcnt(0)" ::: "memory");
        __builtin_amdgcn_s_barrier();
        // phase B: t6[X*16+Y][z] = sum_y t5[X*72+y*8+z] * fo1[Y,y]
        {
            const int X = t >> 3, z = t & 7;
            float a16[16] = {0,0,0,0,0,0,0,0,0,0,0,0,0,0,0,0};
            #pragma unroll
            for (int y = 0; y < 8; ++y) {
                float v = t5[half][X * 72 + y * 8 + z];
                #pragma unroll
                for (int Y = 0; Y < 16; ++Y) a16[Y] += v * fac[1][Y * 8 + y];
            }
            #pragma unroll
            for (int Y = 0; Y < 16; ++Y) t6[half][(X * 16 + Y) * 9 + z] = a16[Y];
        }
        asm volatile("s_waitcnt lgkmcnt(0)" ::: "memory");
        __builtin_amdgcn_s_barrier();
        // phase C: out = (sum_z t6 * fo2) * pds*alpha + bias, float4 stores
        {
            float* orow = out + (size_t)n * D;
            #pragma unroll
            for (int h2 = 0; h2 < 2; ++h2) {
                const int XY = h2 * 128 + t;
                float a16[16] = {0,0,0,0,0,0,0,0,0,0,0,0,0,0,0,0};
                #pragma unroll
                for (int z = 0; z < 8; ++z) {
                    float v = t6[half][XY * 9 + z];
                    #pragma unroll
                    for (int Z = 0; Z < 16; ++Z) a16[Z] += v * fac[2][Z * 8 + z];
                }
                const int j0 = (XY >> 4) * 256 + (XY & 15) * 16;
                #pragma unroll
                for (int w = 0; w < 4; ++w) {
                    float4 ov;
                    ov.x = a16[w * 4 + 0] * pv[h2][w * 4 + 0] + bv[h2][w * 4 + 0];
                    ov.y = a16[w * 4 + 1] * pv[h2][w * 4 + 1] + bv[h2][w * 4 + 1];
                    ov.z = a16[w * 4 + 2] * pv[h2][w * 4 + 2] + bv[h2][w * 4 + 2];
                    ov.w = a16[w * 4 + 3] * pv[h2][w * 4 + 3] + bv[h2][w * 4 + 3];
                    *(float4*)&orow[j0 + w * 4] = ov;
                }
            }
        }
    };

    stage(0);
    stage(1);
    asm volatile("s_waitcnt vmcnt(1) lgkmcnt(0)" ::: "memory");
    __builtin_amdgcn_s_barrier();
    PAIR(0);                                       // +8 stores
    PAIR(1);                                       // +8 stores (buf0 again, no gate)
    asm volatile("s_waitcnt vmcnt(16)" ::: "memory");  // stage(1) done; stores float
    __builtin_amdgcn_s_barrier();
    PAIR(2);
    PAIR(3);
}

extern "C" void kernel_launch(void* const* d_in, const int* in_sizes, int n_in,
                              void* d_out, int out_size, void* d_ws, size_t ws_size,
                              hipStream_t stream) {
    const float* x     = (const float*)d_in[0];
    const float* core  = (const float*)d_in[1];
    const float* fi0   = (const float*)d_in[2];
    const float* fi1   = (const float*)d_in[3];
    const float* fi2   = (const float*)d_in[4];
    const float* fo0   = (const float*)d_in[5];
    const float* fo1   = (const float*)d_in[6];
    const float* fo2   = (const float*)d_in[7];
    const float* pds   = (const float*)d_in[8];
    const float* alpha = (const float*)d_in[9];
    const float* bias  = (const float*)d_in[10];
    const int*   perm  = (const int*)d_in[11];
    float* outp = (float*)d_out;

    char* ws = (char*)d_ws;
    unsigned int*   cb   = (unsigned int*)(ws);                   // 512 KB
    unsigned int*   t3ws = (unsigned int*)(ws + 1048576);         // 16 MB
    unsigned short* t4   = (unsigned short*)(ws + 17825792);      // 16.75 MB

    k_corebf<<<512, 256, 0, stream>>>(core, cb);
    k_t3<<<NROWS / 4, 256, 0, stream>>>(x, fi0, fi1, fi2, perm, t3ws);
    k_core<<<512, 256, 0, stream>>>((const __bf16*)t3ws, (const __bf16*)cb, t4);
    k_expand<<<NROWS / 8, 256, 0, stream>>>(t4, fo0, fo1, fo2, pds, alpha, bias, outp);
}